// Round 3
// baseline (431.783 us; speedup 1.0000x reference)
//
#include <hip/hip_runtime.h>

typedef float f32x4 __attribute__((ext_vector_type(4)));
typedef __bf16 bf16x8 __attribute__((ext_vector_type(8)));

constexpr float INV_SQRT_F = 0.17677669529663687f;  // 32^-0.5

__device__ __forceinline__ f32x4 mfma16(bf16x8 a, bf16x8 b) {
  const f32x4 z = {0.f, 0.f, 0.f, 0.f};
  return __builtin_amdgcn_mfma_f32_16x16x32_bf16(a, b, z, 0, 0, 0);
}

__device__ __forceinline__ bf16x8 load_frag8(const float* __restrict__ p) {
  f32x4 u = *reinterpret_cast<const f32x4*>(p);
  f32x4 v = *reinterpret_cast<const f32x4*>(p + 4);
  bf16x8 r;
  r[0] = (__bf16)u[0]; r[1] = (__bf16)u[1]; r[2] = (__bf16)u[2]; r[3] = (__bf16)u[3];
  r[4] = (__bf16)v[0]; r[5] = (__bf16)v[1]; r[6] = (__bf16)v[2]; r[7] = (__bf16)v[3];
  return r;
}

// Wave-pair structure: waves (2t, 2t+1) of a block handle the SAME 16-edge
// tile; wave parity picks the output-feature half (0-15 / 16-31). Per-phase
// __syncthreads() keeps the pair lock-step so the two 64B sector touches of
// every g-line / out-line are temporally adjacent -> single 128B line fetch,
// single full-line writeback (fixes the 2x FETCH / 2.3x WRITE seen in R2).
// MFMA 16x16x32 bf16 mapping:
//   A: lane holds row m=lane&15 (edge), k=(lane>>4)*8+j (feature in)
//   B: lane holds col n=lane&15 (feature out), k=(lane>>4)*8+j  -> W[g][k]
//   D: lane holds col n=lane&15 (g), rows (lane>>4)*4+reg (edges)
__global__ __launch_bounds__(256, 4)
void leibniz_fused(const float* __restrict__ h0, const float* __restrict__ h1,
                   const float* __restrict__ h2, const float* __restrict__ g0,
                   const float* __restrict__ g1, const float* __restrict__ g2,
                   const float* __restrict__ Wg, const int* __restrict__ src,
                   float* __restrict__ out, int E)
{
  // W staged as bf16 fragments: [path][half][kchunk q][g_lo] of 8 bf16 (16B)
  __shared__ bf16x8 wlds[12 * 2 * 4 * 16];

  for (int c = threadIdx.x; c < 12 * 2 * 4 * 16; c += 256) {
    const int gl = c & 15;
    const int qq = (c >> 4) & 3;
    const int hf = (c >> 6) & 1;
    const int p  = c >> 7;
    const float* wp = Wg + (p * 32 + hf * 16 + gl) * 32 + qq * 8;
    bf16x8 f;
#pragma unroll
    for (int j = 0; j < 8; ++j) f[j] = (__bf16)(wp[j] * INV_SQRT_F);
    wlds[c] = f;
  }
  __syncthreads();

  const int lane = threadIdx.x & 63;
  const int wid  = threadIdx.x >> 6;
  const int half = wid & 1;     // output-feature half handled by this wave
  const int tile = wid >> 1;    // edge-tile within block
  const int m16  = lane & 15;   // A-row edge / B-col feature
  const int q    = lane >> 4;   // k-chunk selector; D-row group
  int e0 = (blockIdx.x * 2 + tile) * 16;
  if (e0 > E - 16) e0 = E - 16;  // clamp (benign duplicate work); keeps barriers uniform

  const int node = src[e0 + m16];
  const int k0 = q * 8;

  // gathered A fragments (bf16) — loaded once, reused by all 12 paths
  const bf16x8 a0 = load_frag8(h0 + node * 32 + k0);
  bf16x8 a1[3];
#pragma unroll
  for (int s = 0; s < 3; ++s) a1[s] = load_frag8(h1 + node * 96 + s * 32 + k0);
  bf16x8 a2[9];
#pragma unroll
  for (int s = 0; s < 9; ++s) a2[s] = load_frag8(h2 + node * 288 + s * 32 + k0);

  const int er0 = e0 + q * 4;       // first of this lane's 4 output edges
  const int o1base = E * 32;
  const int o2base = E * 128;
  const int gc = m16 + 16 * half;   // output feature column

  const f32x4 z4 = {0.f, 0.f, 0.f, 0.f};
  f32x4 acc0 = z4;
  f32x4 acc1[3] = {z4, z4, z4};
  f32x4 acc2[9] = {z4, z4, z4, z4, z4, z4, z4, z4, z4};

#define WFRAG(P) (wlds[(((P) * 2 + half) * 4 + q) * 16 + m16])

  // ---- g0 phase: paths 0 (0,0->0 prod), 3 (1,0->1 prod), 4 (2,0->2 prod)
  __syncthreads();  // pair-sync: co-time the two 64B sector reads per line
  {
    f32x4 g0v;
#pragma unroll
    for (int r = 0; r < 4; ++r) g0v[r] = g0[(er0 + r) * 32 + gc];
    {
      const bf16x8 wb = WFRAG(0);
      acc0 += mfma16(a0, wb) * g0v;
    }
    {
      const bf16x8 wb = WFRAG(3);
#pragma unroll
      for (int s = 0; s < 3; ++s) acc1[s] += mfma16(a1[s], wb) * g0v;
    }
    {
      const bf16x8 wb = WFRAG(4);
#pragma unroll
      for (int s = 0; s < 9; ++s) acc2[s] += mfma16(a2[s], wb) * g0v;
    }
  }

  // ---- g1 phase: paths 1 (prod), 5 (dot), 6 (cross), 7 (outer), 8 (mat_vec)
  __syncthreads();
  {
    f32x4 g1v[3];
#pragma unroll
    for (int s = 0; s < 3; ++s)
#pragma unroll
      for (int r = 0; r < 4; ++r)
        g1v[s][r] = g1[((er0 + r) * 3 + s) * 32 + gc];
    {
      const bf16x8 wb = WFRAG(1);
      const f32x4 t = mfma16(a0, wb);
#pragma unroll
      for (int s = 0; s < 3; ++s) acc1[s] += t * g1v[s];
    }
    {
      const bf16x8 wb = WFRAG(5);
#pragma unroll
      for (int s = 0; s < 3; ++s) acc0 += mfma16(a1[s], wb) * g1v[s];
    }
    {
      const bf16x8 wb = WFRAG(6);
      const f32x4 c0 = mfma16(a1[0], wb);
      const f32x4 c1 = mfma16(a1[1], wb);
      const f32x4 c2 = mfma16(a1[2], wb);
      acc1[0] += c1 * g1v[2] - c2 * g1v[1];
      acc1[1] += c2 * g1v[0] - c0 * g1v[2];
      acc1[2] += c0 * g1v[1] - c1 * g1v[0];
    }
    {
      const bf16x8 wb = WFRAG(7);
      const f32x4 o0 = mfma16(a1[0], wb);
      const f32x4 o1 = mfma16(a1[1], wb);
      const f32x4 o2 = mfma16(a1[2], wb);
      const f32x4 tr3 = (o0 * g1v[0] + o1 * g1v[1] + o2 * g1v[2]) * (1.f / 3.f);
      acc2[0] += o0 * g1v[0] - tr3;
      acc2[1] += o0 * g1v[1];
      acc2[2] += o0 * g1v[2];
      acc2[3] += o1 * g1v[0];
      acc2[4] += o1 * g1v[1] - tr3;
      acc2[5] += o1 * g1v[2];
      acc2[6] += o2 * g1v[0];
      acc2[7] += o2 * g1v[1];
      acc2[8] += o2 * g1v[2] - tr3;
    }
    {
      const bf16x8 wb = WFRAG(8);
#pragma unroll
      for (int i = 0; i < 3; ++i)
#pragma unroll
        for (int j = 0; j < 3; ++j)
          acc1[i] += mfma16(a2[i * 3 + j], wb) * g1v[j];
    }
  }

  // ---- g2 phase: paths 2 (prod), 9 (vec_mat), 10 (double_dot), 11 (mat_mul_sym)
  __syncthreads();
  {
    f32x4 g2v[9];
#pragma unroll
    for (int s = 0; s < 9; ++s)
#pragma unroll
      for (int r = 0; r < 4; ++r)
        g2v[s][r] = g2[((er0 + r) * 9 + s) * 32 + gc];
    {
      const bf16x8 wb = WFRAG(2);
      const f32x4 t = mfma16(a0, wb);
#pragma unroll
      for (int s = 0; s < 9; ++s) acc2[s] += t * g2v[s];
    }
    {
      const bf16x8 wb = WFRAG(9);
      const f32x4 v0 = mfma16(a1[0], wb);
      const f32x4 v1 = mfma16(a1[1], wb);
      const f32x4 v2 = mfma16(a1[2], wb);
#pragma unroll
      for (int j = 0; j < 3; ++j)
        acc1[j] += v0 * g2v[0 * 3 + j] + v1 * g2v[1 * 3 + j] + v2 * g2v[2 * 3 + j];
    }
    {
      const bf16x8 wb = WFRAG(10);
#pragma unroll
      for (int s = 0; s < 9; ++s) acc0 += mfma16(a2[s], wb) * g2v[s];
    }
    {
      // raw_ij = sum_k ht[i][k] g2[k][j]; out2 += 0.5(raw+raw^T) - (tr/3) I
      const bf16x8 wb = WFRAG(11);
#pragma unroll
      for (int k = 0; k < 3; ++k) {
        const f32x4 m0 = mfma16(a2[0 * 3 + k], wb);
        const f32x4 m1 = mfma16(a2[1 * 3 + k], wb);
        const f32x4 m2 = mfma16(a2[2 * 3 + k], wb);
        const f32x4 gk0 = g2v[k * 3 + 0];
        const f32x4 gk1 = g2v[k * 3 + 1];
        const f32x4 gk2 = g2v[k * 3 + 2];
        const f32x4 tk3 = (m0 * gk0 + m1 * gk1 + m2 * gk2) * (1.f / 3.f);
        acc2[0] += m0 * gk0 - tk3;
        acc2[4] += m1 * gk1 - tk3;
        acc2[8] += m2 * gk2 - tk3;
        const f32x4 s01 = (m0 * gk1 + m1 * gk0) * 0.5f;
        acc2[1] += s01; acc2[3] += s01;
        const f32x4 s02 = (m0 * gk2 + m2 * gk0) * 0.5f;
        acc2[2] += s02; acc2[6] += s02;
        const f32x4 s12 = (m1 * gk2 + m2 * gk1) * 0.5f;
        acc2[5] += s12; acc2[7] += s12;
      }
    }
  }

  // ---- stores (pair writes the two 64B halves of each line back-to-back)
  __syncthreads();
#pragma unroll
  for (int r = 0; r < 4; ++r) out[(er0 + r) * 32 + gc] = acc0[r];
#pragma unroll
  for (int s = 0; s < 3; ++s)
#pragma unroll
    for (int r = 0; r < 4; ++r)
      out[o1base + ((er0 + r) * 3 + s) * 32 + gc] = acc1[s][r];
#pragma unroll
  for (int s = 0; s < 9; ++s)
#pragma unroll
    for (int r = 0; r < 4; ++r)
      out[o2base + ((er0 + r) * 9 + s) * 32 + gc] = acc2[s][r];
#undef WFRAG
}

extern "C" void kernel_launch(void* const* d_in, const int* in_sizes, int n_in,
                              void* d_out, int out_size, void* d_ws, size_t ws_size,
                              hipStream_t stream) {
  const float* h0 = (const float*)d_in[0];
  const float* h1 = (const float*)d_in[1];
  const float* h2 = (const float*)d_in[2];
  const float* g0 = (const float*)d_in[3];
  const float* g1 = (const float*)d_in[4];
  const float* g2 = (const float*)d_in[5];
  const float* Wg = (const float*)d_in[6];
  const int* src = (const int*)d_in[7];  // harness passes integer inputs as int32
  const int E = in_sizes[7];
  const int blocks = (E + 31) / 32;  // 4 waves = 2 edge-tiles x 2 feature-halves
  leibniz_fused<<<blocks, 256, 0, stream>>>(h0, h1, h2, g0, g1, g2, Wg, src,
                                            (float*)d_out, E);
}

// Round 4
// 131.075 us; speedup vs baseline: 3.2942x; 3.2942x over previous
//
#include <hip/hip_runtime.h>

typedef float f32x4 __attribute__((ext_vector_type(4)));
typedef __bf16 bf16x8 __attribute__((ext_vector_type(8)));

constexpr float INV_SQRT_F = 0.17677669529663687f;  // 32^-0.5

__device__ __forceinline__ f32x4 mfma16(bf16x8 a, bf16x8 b) {
  const f32x4 z = {0.f, 0.f, 0.f, 0.f};
  return __builtin_amdgcn_mfma_f32_16x16x32_bf16(a, b, z, 0, 0, 0);
}

__device__ __forceinline__ bf16x8 load_frag8(const float* __restrict__ p) {
  f32x4 u = *reinterpret_cast<const f32x4*>(p);
  f32x4 v = *reinterpret_cast<const f32x4*>(p + 4);
  bf16x8 r;
  r[0] = (__bf16)u[0]; r[1] = (__bf16)u[1]; r[2] = (__bf16)u[2]; r[3] = (__bf16)u[3];
  r[4] = (__bf16)v[0]; r[5] = (__bf16)v[1]; r[6] = (__bf16)v[2]; r[7] = (__bf16)v[3];
  return r;
}

// Transposed MFMA roles vs R2:  D = A*B with
//   A = W fragment : row m=lane&15 -> OUTPUT feature (within half), k=(lane>>4)*8+j
//   B = h gathered : col n=lane&15 -> EDGE, k=(lane>>4)*8+j
//   D : col=lane&15 = edge, rows=(lane>>4)*4+r = output features 4q..4q+3 (+16*half)
// => each lane owns a contiguous float4 of features for ONE edge. All g reads
// and out writes are float4; the two 16B halves (+16 features) issue
// back-to-back in the SAME wave, so every 128B line is fully consumed per
// touch — no dependence on L2 line residency across phases/waves (R2's 2x
// fetch / 2.3x write). One wave = 16 edges, both halves (dual accumulators).
__global__ __launch_bounds__(256, 2)
void leibniz_fused(const float* __restrict__ h0, const float* __restrict__ h1,
                   const float* __restrict__ h2, const float* __restrict__ g0,
                   const float* __restrict__ g1, const float* __restrict__ g2,
                   const float* __restrict__ Wg, const int* __restrict__ src,
                   float* __restrict__ out, int E)
{
  // W staged as bf16 A-fragments: [path][half][kchunk q][m] of 8 bf16 (16B),
  // entry (p,h,q,m) = W[p][m + 16h][8q..8q+7] * INV_SQRT_F
  __shared__ bf16x8 wlds[12 * 2 * 4 * 16];

  for (int c = threadIdx.x; c < 12 * 2 * 4 * 16; c += 256) {
    const int gl = c & 15;
    const int qq = (c >> 4) & 3;
    const int hf = (c >> 6) & 1;
    const int p  = c >> 7;
    const float* wp = Wg + (p * 32 + hf * 16 + gl) * 32 + qq * 8;
    bf16x8 f;
#pragma unroll
    for (int j = 0; j < 8; ++j) f[j] = (__bf16)(wp[j] * INV_SQRT_F);
    wlds[c] = f;
  }
  __syncthreads();

  const int lane = threadIdx.x & 63;
  const int wid  = threadIdx.x >> 6;
  const int eidx = lane & 15;   // edge within tile (B col / W-frag row index)
  const int q    = lane >> 4;   // k-chunk; D feature-row group
  int e0 = (blockIdx.x * 4 + wid) * 16;
  if (e0 > E - 16) e0 = E - 16;  // benign clamp

  const int node = src[e0 + eidx];
  const int k0 = q * 8;

  // gathered B fragments (bf16) — loaded once, reused by all 12 paths
  const bf16x8 b0 = load_frag8(h0 + node * 32 + k0);
  bf16x8 b1[3];
#pragma unroll
  for (int s = 0; s < 3; ++s) b1[s] = load_frag8(h1 + node * 96 + s * 32 + k0);
  bf16x8 b2[9];
#pragma unroll
  for (int s = 0; s < 9; ++s) b2[s] = load_frag8(h2 + node * 288 + s * 32 + k0);

  const int e   = e0 + eidx;   // this lane's edge
  const int col = q * 4;       // first of the lane's 4 feature columns (half 0)
  const float* g0p = g0 + e * 32 + col;
  const float* g1p = g1 + (long long)e * 96 + col;
  const float* g2p = g2 + (long long)e * 288 + col;
  float* o0p = out + (long long)e * 32 + col;
  float* o1p = out + (long long)E * 32 + (long long)e * 96 + col;
  float* o2p = out + (long long)E * 128 + (long long)e * 288 + col;

  const f32x4 z4 = {0.f, 0.f, 0.f, 0.f};
  f32x4 acc0[2] = {z4, z4};
  f32x4 acc1[3][2];
  f32x4 acc2[9][2];
#pragma unroll
  for (int s = 0; s < 3; ++s) { acc1[s][0] = z4; acc1[s][1] = z4; }
#pragma unroll
  for (int s = 0; s < 9; ++s) { acc2[s][0] = z4; acc2[s][1] = z4; }

#define WFRAG(P, H) (wlds[(((P) * 2 + (H)) * 4 + q) * 16 + eidx])

  // ---- g0 phase: paths 0 (0,0->0), 3 (1,0->1), 4 (2,0->2), all 'prod'
  {
    f32x4 gv[2];
    gv[0] = *reinterpret_cast<const f32x4*>(g0p);
    gv[1] = *reinterpret_cast<const f32x4*>(g0p + 16);
#pragma unroll
    for (int h = 0; h < 2; ++h) {
      acc0[h] += mfma16(WFRAG(0, h), b0) * gv[h];
      const bf16x8 w3 = WFRAG(3, h);
#pragma unroll
      for (int s = 0; s < 3; ++s) acc1[s][h] += mfma16(w3, b1[s]) * gv[h];
      const bf16x8 w4 = WFRAG(4, h);
#pragma unroll
      for (int s = 0; s < 9; ++s) acc2[s][h] += mfma16(w4, b2[s]) * gv[h];
    }
  }

  // ---- g1 phase: paths 1 (prod), 5 (dot), 6 (cross), 7 (outer), 8 (mat_vec)
  {
    f32x4 gv[3][2];
#pragma unroll
    for (int s = 0; s < 3; ++s) {
      gv[s][0] = *reinterpret_cast<const f32x4*>(g1p + s * 32);
      gv[s][1] = *reinterpret_cast<const f32x4*>(g1p + s * 32 + 16);
    }
#pragma unroll
    for (int h = 0; h < 2; ++h) {
      {
        const f32x4 t = mfma16(WFRAG(1, h), b0);
#pragma unroll
        for (int s = 0; s < 3; ++s) acc1[s][h] += t * gv[s][h];
      }
      {
        const bf16x8 w5 = WFRAG(5, h);
#pragma unroll
        for (int s = 0; s < 3; ++s) acc0[h] += mfma16(w5, b1[s]) * gv[s][h];
      }
      {
        const bf16x8 w6 = WFRAG(6, h);
        const f32x4 c0 = mfma16(w6, b1[0]);
        const f32x4 c1 = mfma16(w6, b1[1]);
        const f32x4 c2 = mfma16(w6, b1[2]);
        acc1[0][h] += c1 * gv[2][h] - c2 * gv[1][h];
        acc1[1][h] += c2 * gv[0][h] - c0 * gv[2][h];
        acc1[2][h] += c0 * gv[1][h] - c1 * gv[0][h];
      }
      {
        const bf16x8 w7 = WFRAG(7, h);
        const f32x4 o0 = mfma16(w7, b1[0]);
        const f32x4 o1 = mfma16(w7, b1[1]);
        const f32x4 o2 = mfma16(w7, b1[2]);
        const f32x4 tr3 = (o0 * gv[0][h] + o1 * gv[1][h] + o2 * gv[2][h]) * (1.f / 3.f);
        acc2[0][h] += o0 * gv[0][h] - tr3;
        acc2[1][h] += o0 * gv[1][h];
        acc2[2][h] += o0 * gv[2][h];
        acc2[3][h] += o1 * gv[0][h];
        acc2[4][h] += o1 * gv[1][h] - tr3;
        acc2[5][h] += o1 * gv[2][h];
        acc2[6][h] += o2 * gv[0][h];
        acc2[7][h] += o2 * gv[1][h];
        acc2[8][h] += o2 * gv[2][h] - tr3;
      }
      {
        const bf16x8 w8 = WFRAG(8, h);
#pragma unroll
        for (int i = 0; i < 3; ++i)
#pragma unroll
          for (int j = 0; j < 3; ++j)
            acc1[i][h] += mfma16(w8, b2[i * 3 + j]) * gv[j][h];
      }
    }
  }

  // ---- g2 phase: paths 2 (prod), 9 (vec_mat), 10 (double_dot), 11 (mat_mul_sym)
  // k-loop keeps only one g2 row (3 cols x 2 halves) live at a time.
  {
    f32x4 t2[2];
    t2[0] = mfma16(WFRAG(2, 0), b0);
    t2[1] = mfma16(WFRAG(2, 1), b0);
#pragma unroll
    for (int k = 0; k < 3; ++k) {
      f32x4 gk[3][2];
#pragma unroll
      for (int j = 0; j < 3; ++j) {
        gk[j][0] = *reinterpret_cast<const f32x4*>(g2p + (k * 3 + j) * 32);
        gk[j][1] = *reinterpret_cast<const f32x4*>(g2p + (k * 3 + j) * 32 + 16);
      }
#pragma unroll
      for (int h = 0; h < 2; ++h) {
        // path 2: prod l0 x g2
#pragma unroll
        for (int j = 0; j < 3; ++j) acc2[k * 3 + j][h] += t2[h] * gk[j][h];
        // path 9: vec_mat  res_j = sum_i ht1_i g2[i][j]  (i == k here)
        {
          const f32x4 vk = mfma16(WFRAG(9, h), b1[k]);
#pragma unroll
          for (int j = 0; j < 3; ++j) acc1[j][h] += vk * gk[j][h];
        }
        // path 10: double_dot
        {
          const bf16x8 w10 = WFRAG(10, h);
#pragma unroll
          for (int j = 0; j < 3; ++j) acc0[h] += mfma16(w10, b2[k * 3 + j]) * gk[j][h];
        }
        // path 11: mat_mul_sym  raw_ij^k = (W ht2)[i][k] * g2[k][j]
        {
          const bf16x8 w11 = WFRAG(11, h);
          const f32x4 m0 = mfma16(w11, b2[0 * 3 + k]);
          const f32x4 m1 = mfma16(w11, b2[1 * 3 + k]);
          const f32x4 m2 = mfma16(w11, b2[2 * 3 + k]);
          const f32x4 tk3 = (m0 * gk[0][h] + m1 * gk[1][h] + m2 * gk[2][h]) * (1.f / 3.f);
          acc2[0][h] += m0 * gk[0][h] - tk3;
          acc2[4][h] += m1 * gk[1][h] - tk3;
          acc2[8][h] += m2 * gk[2][h] - tk3;
          const f32x4 s01 = (m0 * gk[1][h] + m1 * gk[0][h]) * 0.5f;
          acc2[1][h] += s01; acc2[3][h] += s01;
          const f32x4 s02 = (m0 * gk[2][h] + m2 * gk[0][h]) * 0.5f;
          acc2[2][h] += s02; acc2[6][h] += s02;
          const f32x4 s12 = (m1 * gk[2][h] + m2 * gk[1][h]) * 0.5f;
          acc2[5][h] += s12; acc2[7][h] += s12;
        }
      }
    }
  }

  // ---- stores: float4 pairs -> each 128B line fully written by this wave
  *reinterpret_cast<f32x4*>(o0p)      = acc0[0];
  *reinterpret_cast<f32x4*>(o0p + 16) = acc0[1];
#pragma unroll
  for (int s = 0; s < 3; ++s) {
    *reinterpret_cast<f32x4*>(o1p + s * 32)      = acc1[s][0];
    *reinterpret_cast<f32x4*>(o1p + s * 32 + 16) = acc1[s][1];
  }
#pragma unroll
  for (int s = 0; s < 9; ++s) {
    *reinterpret_cast<f32x4*>(o2p + s * 32)      = acc2[s][0];
    *reinterpret_cast<f32x4*>(o2p + s * 32 + 16) = acc2[s][1];
  }
#undef WFRAG
}

extern "C" void kernel_launch(void* const* d_in, const int* in_sizes, int n_in,
                              void* d_out, int out_size, void* d_ws, size_t ws_size,
                              hipStream_t stream) {
  const float* h0 = (const float*)d_in[0];
  const float* h1 = (const float*)d_in[1];
  const float* h2 = (const float*)d_in[2];
  const float* g0 = (const float*)d_in[3];
  const float* g1 = (const float*)d_in[4];
  const float* g2 = (const float*)d_in[5];
  const float* Wg = (const float*)d_in[6];
  const int* src = (const int*)d_in[7];  // harness passes integer inputs as int32
  const int E = in_sizes[7];
  const int blocks = (E + 63) / 64;  // 4 waves x 16 edges
  leibniz_fused<<<blocks, 256, 0, stream>>>(h0, h1, h2, g0, g1, g2, Wg, src,
                                            (float*)d_out, E);
}

// Round 5
// 126.882 us; speedup vs baseline: 3.4030x; 1.0330x over previous
//
#include <hip/hip_runtime.h>

typedef float f32x4 __attribute__((ext_vector_type(4)));
typedef __bf16 bf16x8 __attribute__((ext_vector_type(8)));

constexpr float INV_SQRT_F = 0.17677669529663687f;  // 32^-0.5

__device__ __forceinline__ f32x4 mfma16(bf16x8 a, bf16x8 b) {
  const f32x4 z = {0.f, 0.f, 0.f, 0.f};
  return __builtin_amdgcn_mfma_f32_16x16x32_bf16(a, b, z, 0, 0, 0);
}

__device__ __forceinline__ bf16x8 load_frag8(const float* __restrict__ p) {
  f32x4 u = *reinterpret_cast<const f32x4*>(p);
  f32x4 v = *reinterpret_cast<const f32x4*>(p + 4);
  bf16x8 r;
  r[0] = (__bf16)u[0]; r[1] = (__bf16)u[1]; r[2] = (__bf16)u[2]; r[3] = (__bf16)u[3];
  r[4] = (__bf16)v[0]; r[5] = (__bf16)v[1]; r[6] = (__bf16)v[2]; r[7] = (__bf16)v[3];
  return r;
}

__device__ __forceinline__ f32x4 ntload4(const float* __restrict__ p) {
  return __builtin_nontemporal_load(reinterpret_cast<const f32x4*>(p));
}
__device__ __forceinline__ void ntstore4(float* __restrict__ p, f32x4 v) {
  __builtin_nontemporal_store(v, reinterpret_cast<f32x4*>(p));
}

// Layout as R4 (transposed MFMA roles; lane owns a contiguous feature float4
// of one edge for both halves). R5 change: memory-level parallelism.
//  - g0+g1 issued before the h gather/cvt (HBM latency overlaps L3 gather).
//  - g2 rows software-pipelined: row k+1 issued before row k compute.
//  - g loads / out stores nontemporal (single-touch streams; keep L2 for h).
__global__ __launch_bounds__(256, 2)
void leibniz_fused(const float* __restrict__ h0, const float* __restrict__ h1,
                   const float* __restrict__ h2, const float* __restrict__ g0,
                   const float* __restrict__ g1, const float* __restrict__ g2,
                   const float* __restrict__ Wg, const int* __restrict__ src,
                   float* __restrict__ out, int E)
{
  // W staged as bf16 A-fragments: [path][half][kchunk q][m] of 8 bf16 (16B),
  // entry (p,h,q,m) = W[p][m + 16h][8q..8q+7] * INV_SQRT_F
  __shared__ bf16x8 wlds[12 * 2 * 4 * 16];

  for (int c = threadIdx.x; c < 12 * 2 * 4 * 16; c += 256) {
    const int gl = c & 15;
    const int qq = (c >> 4) & 3;
    const int hf = (c >> 6) & 1;
    const int p  = c >> 7;
    const float* wp = Wg + (p * 32 + hf * 16 + gl) * 32 + qq * 8;
    bf16x8 f;
#pragma unroll
    for (int j = 0; j < 8; ++j) f[j] = (__bf16)(wp[j] * INV_SQRT_F);
    wlds[c] = f;
  }
  __syncthreads();

  const int lane = threadIdx.x & 63;
  const int wid  = threadIdx.x >> 6;
  const int eidx = lane & 15;   // edge within tile (B col / W-frag row index)
  const int q    = lane >> 4;   // k-chunk; D feature-row group
  int e0 = (blockIdx.x * 4 + wid) * 16;
  if (e0 > E - 16) e0 = E - 16;  // benign clamp

  const int node = src[e0 + eidx];   // issue gather index load first

  const int e   = e0 + eidx;   // this lane's edge
  const int col = q * 4;       // first of the lane's 4 feature columns (half 0)
  const float* g0p = g0 + e * 32 + col;
  const float* g1p = g1 + (long long)e * 96 + col;
  const float* g2p = g2 + (long long)e * 288 + col;

  // ---- early-issue g0 + g1 (8 nontemporal loads in flight over h gather)
  f32x4 gv0[2];
  gv0[0] = ntload4(g0p);
  gv0[1] = ntload4(g0p + 16);
  f32x4 gv1[3][2];
#pragma unroll
  for (int s = 0; s < 3; ++s) {
    gv1[s][0] = ntload4(g1p + s * 32);
    gv1[s][1] = ntload4(g1p + s * 32 + 16);
  }

  // ---- h gather + cvt (L3-resident; overlaps the g HBM latency)
  const int k0 = q * 8;
  const bf16x8 b0 = load_frag8(h0 + node * 32 + k0);
  bf16x8 b1[3];
#pragma unroll
  for (int s = 0; s < 3; ++s) b1[s] = load_frag8(h1 + node * 96 + s * 32 + k0);
  bf16x8 b2[9];
#pragma unroll
  for (int s = 0; s < 9; ++s) b2[s] = load_frag8(h2 + node * 288 + s * 32 + k0);

  const f32x4 z4 = {0.f, 0.f, 0.f, 0.f};
  f32x4 acc0[2] = {z4, z4};
  f32x4 acc1[3][2];
  f32x4 acc2[9][2];
#pragma unroll
  for (int s = 0; s < 3; ++s) { acc1[s][0] = z4; acc1[s][1] = z4; }
#pragma unroll
  for (int s = 0; s < 9; ++s) { acc2[s][0] = z4; acc2[s][1] = z4; }

#define WFRAG(P, H) (wlds[(((P) * 2 + (H)) * 4 + q) * 16 + eidx])

  // ---- g0 phase: paths 0 (0,0->0), 3 (1,0->1), 4 (2,0->2), all 'prod'
#pragma unroll
  for (int h = 0; h < 2; ++h) {
    acc0[h] += mfma16(WFRAG(0, h), b0) * gv0[h];
    const bf16x8 w3 = WFRAG(3, h);
#pragma unroll
    for (int s = 0; s < 3; ++s) acc1[s][h] += mfma16(w3, b1[s]) * gv0[h];
    const bf16x8 w4 = WFRAG(4, h);
#pragma unroll
    for (int s = 0; s < 9; ++s) acc2[s][h] += mfma16(w4, b2[s]) * gv0[h];
  }

  // ---- issue g2 row 0 (pipeline ahead of g1 compute)
  f32x4 gkA[3][2];
#pragma unroll
  for (int j = 0; j < 3; ++j) {
    gkA[j][0] = ntload4(g2p + j * 32);
    gkA[j][1] = ntload4(g2p + j * 32 + 16);
  }

  // ---- g1 phase: paths 1 (prod), 5 (dot), 6 (cross), 7 (outer), 8 (mat_vec)
#pragma unroll
  for (int h = 0; h < 2; ++h) {
    {
      const f32x4 t = mfma16(WFRAG(1, h), b0);
#pragma unroll
      for (int s = 0; s < 3; ++s) acc1[s][h] += t * gv1[s][h];
    }
    {
      const bf16x8 w5 = WFRAG(5, h);
#pragma unroll
      for (int s = 0; s < 3; ++s) acc0[h] += mfma16(w5, b1[s]) * gv1[s][h];
    }
    {
      const bf16x8 w6 = WFRAG(6, h);
      const f32x4 c0 = mfma16(w6, b1[0]);
      const f32x4 c1 = mfma16(w6, b1[1]);
      const f32x4 c2 = mfma16(w6, b1[2]);
      acc1[0][h] += c1 * gv1[2][h] - c2 * gv1[1][h];
      acc1[1][h] += c2 * gv1[0][h] - c0 * gv1[2][h];
      acc1[2][h] += c0 * gv1[1][h] - c1 * gv1[0][h];
    }
    {
      const bf16x8 w7 = WFRAG(7, h);
      const f32x4 o0 = mfma16(w7, b1[0]);
      const f32x4 o1 = mfma16(w7, b1[1]);
      const f32x4 o2 = mfma16(w7, b1[2]);
      const f32x4 tr3 = (o0 * gv1[0][h] + o1 * gv1[1][h] + o2 * gv1[2][h]) * (1.f / 3.f);
      acc2[0][h] += o0 * gv1[0][h] - tr3;
      acc2[1][h] += o0 * gv1[1][h];
      acc2[2][h] += o0 * gv1[2][h];
      acc2[3][h] += o1 * gv1[0][h];
      acc2[4][h] += o1 * gv1[1][h] - tr3;
      acc2[5][h] += o1 * gv1[2][h];
      acc2[6][h] += o2 * gv1[0][h];
      acc2[7][h] += o2 * gv1[1][h];
      acc2[8][h] += o2 * gv1[2][h] - tr3;
    }
    {
      const bf16x8 w8 = WFRAG(8, h);
#pragma unroll
      for (int i = 0; i < 3; ++i)
#pragma unroll
        for (int j = 0; j < 3; ++j)
          acc1[i][h] += mfma16(w8, b2[i * 3 + j]) * gv1[j][h];
    }
  }

  // ---- issue g2 row 1
  f32x4 gkB[3][2];
#pragma unroll
  for (int j = 0; j < 3; ++j) {
    gkB[j][0] = ntload4(g2p + (3 + j) * 32);
    gkB[j][1] = ntload4(g2p + (3 + j) * 32 + 16);
  }

  // ---- g2 phase: paths 2 (prod), 9 (vec_mat), 10 (double_dot), 11 (mat_mul_sym)
  f32x4 t2[2];
  t2[0] = mfma16(WFRAG(2, 0), b0);
  t2[1] = mfma16(WFRAG(2, 1), b0);

#define G2ROW_COMPUTE(K, GK)                                                   \
  {                                                                            \
    _Pragma("unroll")                                                          \
    for (int h = 0; h < 2; ++h) {                                              \
      _Pragma("unroll")                                                        \
      for (int j = 0; j < 3; ++j) acc2[(K) * 3 + j][h] += t2[h] * GK[j][h];    \
      {                                                                        \
        const f32x4 vk = mfma16(WFRAG(9, h), b1[(K)]);                         \
        _Pragma("unroll")                                                      \
        for (int j = 0; j < 3; ++j) acc1[j][h] += vk * GK[j][h];               \
      }                                                                        \
      {                                                                        \
        const bf16x8 w10 = WFRAG(10, h);                                       \
        _Pragma("unroll")                                                      \
        for (int j = 0; j < 3; ++j)                                            \
          acc0[h] += mfma16(w10, b2[(K) * 3 + j]) * GK[j][h];                  \
      }                                                                        \
      {                                                                        \
        const bf16x8 w11 = WFRAG(11, h);                                       \
        const f32x4 m0 = mfma16(w11, b2[0 * 3 + (K)]);                         \
        const f32x4 m1 = mfma16(w11, b2[1 * 3 + (K)]);                         \
        const f32x4 m2 = mfma16(w11, b2[2 * 3 + (K)]);                         \
        const f32x4 tk3 =                                                      \
            (m0 * GK[0][h] + m1 * GK[1][h] + m2 * GK[2][h]) * (1.f / 3.f);     \
        acc2[0][h] += m0 * GK[0][h] - tk3;                                     \
        acc2[4][h] += m1 * GK[1][h] - tk3;                                     \
        acc2[8][h] += m2 * GK[2][h] - tk3;                                     \
        const f32x4 s01 = (m0 * GK[1][h] + m1 * GK[0][h]) * 0.5f;              \
        acc2[1][h] += s01; acc2[3][h] += s01;                                  \
        const f32x4 s02 = (m0 * GK[2][h] + m2 * GK[0][h]) * 0.5f;              \
        acc2[2][h] += s02; acc2[6][h] += s02;                                  \
        const f32x4 s12 = (m1 * GK[2][h] + m2 * GK[1][h]) * 0.5f;              \
        acc2[5][h] += s12; acc2[7][h] += s12;                                  \
      }                                                                        \
    }                                                                          \
  }

  G2ROW_COMPUTE(0, gkA)

  // ---- issue g2 row 2 (reuse gkA registers)
#pragma unroll
  for (int j = 0; j < 3; ++j) {
    gkA[j][0] = ntload4(g2p + (6 + j) * 32);
    gkA[j][1] = ntload4(g2p + (6 + j) * 32 + 16);
  }

  G2ROW_COMPUTE(1, gkB)
  G2ROW_COMPUTE(2, gkA)

#undef G2ROW_COMPUTE

  // ---- stores: nontemporal float4 pairs; wave covers full 128B lines
  float* o0p = out + (long long)e * 32 + col;
  float* o1p = out + (long long)E * 32 + (long long)e * 96 + col;
  float* o2p = out + (long long)E * 128 + (long long)e * 288 + col;

  ntstore4(o0p, acc0[0]);
  ntstore4(o0p + 16, acc0[1]);
#pragma unroll
  for (int s = 0; s < 3; ++s) {
    ntstore4(o1p + s * 32, acc1[s][0]);
    ntstore4(o1p + s * 32 + 16, acc1[s][1]);
  }
#pragma unroll
  for (int s = 0; s < 9; ++s) {
    ntstore4(o2p + s * 32, acc2[s][0]);
    ntstore4(o2p + s * 32 + 16, acc2[s][1]);
  }
#undef WFRAG
}

extern "C" void kernel_launch(void* const* d_in, const int* in_sizes, int n_in,
                              void* d_out, int out_size, void* d_ws, size_t ws_size,
                              hipStream_t stream) {
  const float* h0 = (const float*)d_in[0];
  const float* h1 = (const float*)d_in[1];
  const float* h2 = (const float*)d_in[2];
  const float* g0 = (const float*)d_in[3];
  const float* g1 = (const float*)d_in[4];
  const float* g2 = (const float*)d_in[5];
  const float* Wg = (const float*)d_in[6];
  const int* src = (const int*)d_in[7];  // harness passes integer inputs as int32
  const int E = in_sizes[7];
  const int blocks = (E + 63) / 64;  // 4 waves x 16 edges
  leibniz_fused<<<blocks, 256, 0, stream>>>(h0, h1, h2, g0, g1, g2, Wg, src,
                                            (float*)d_out, E);
}